// Round 9
// baseline (40.031 us; speedup 1.0000x reference)
//
#include <hip/hip_runtime.h>
#include <hip/hip_bf16.h>
#include <math.h>

// loss = w * mean((sim_o - sim_t)^2);  ||OO^T - TT^T||_F^2 =
//   ||O^T O||^2 + ||T^T T||^2 - 2||O^T T||^2   (diag mask is a no-op).
// 3 launches, no global barriers, no heavy atomics (R3/R6/R7 lessons:
// grid barriers ~70us, 6M fp32 atomics ~40us — both forbidden):
//   K1 transpose: normalize + bf16 -> obt [f][k]; LDS b64 gather + reg transpose
//   K2 gram: NO-LDS MFMA — frags are 16B contiguous loads from obt (L2-hot,
//            per-chunk working set 256KB on one XCD); 1-wave blocks, 0 barriers
//   K3 reduce: chunk-sum + Frobenius; last block finalizes out[0].

#define N_ROWS 8192
#define DDIM   256
#define NC     32                    // K chunks
#define KC     (N_ROWS / NC)         // 256 rows / chunk
#define NPOS   64                    // 8x8 positions of 32x32 output
#define PART_STRIDE (3 * NPOS * 1024)  // 196608 ushorts per chunk
#define NRED   96

// ws layout: float ws[0] = scalar acc; u32 ctr at ws[4];
// obt (bf16, 2 matrices [f][k]) at OBT_UOFF ushorts; partials after.
#define OBT_UOFF  32
#define MAT_USZ   (DDIM * N_ROWS)    // 2,097,152 ushorts per matrix
#define PART_UOFF (OBT_UOFF + 2 * MAT_USZ)

typedef __bf16 bf16x8 __attribute__((ext_vector_type(8)));
typedef short  short8 __attribute__((ext_vector_type(8)));
typedef unsigned short us4 __attribute__((ext_vector_type(4)));
typedef unsigned short us8 __attribute__((ext_vector_type(8)));
typedef float  f32x16 __attribute__((ext_vector_type(16)));
typedef unsigned int u32;

__device__ inline unsigned short f2bu(float x) {
    __hip_bfloat16 h = __float2bfloat16(x);
    return __builtin_bit_cast(unsigned short, h);
}
__device__ inline float u2f(unsigned short u) {
    unsigned int v = ((unsigned int)u) << 16;
    return __builtin_bit_cast(float, v);
}

// ---- K1: normalize + bf16 + transpose -> obt [f][k] ----
// 256 blocks: (b&1) matrix, (b>>1)*64 k-rows. Phase 1: coalesced float4 rows,
// wave norm-reduce, ushort4 into LDS [k][f] (stride 260 for 8B align).
// Phase 2: per thread 16 x ds_read_b64 (8 k-rows x f-quad), in-register 8x4
// u16 transpose, 8 x 16B coalesced global stores (128B lines per 8 lanes).
__global__ __launch_bounds__(256) void transpose_kernel(const float* __restrict__ O,
                                                        const float* __restrict__ T,
                                                        float* __restrict__ ws) {
    int tid = threadIdx.x;
    if (blockIdx.x == 0 && tid == 0) {
        ws[0] = 0.0f;
        ((u32*)(ws + 4))[0] = 0u;
    }
    int b = blockIdx.x;
    const float* src = (b & 1) ? T : O;
    unsigned short* dst =
        (unsigned short*)ws + OBT_UOFF + (size_t)(b & 1) * MAT_USZ;
    int kb = (b >> 1) * 64;

    __shared__ unsigned short lt[64 * 260];   // [k][f], stride 260
    int w = tid >> 6, l = tid & 63;
    #pragma unroll
    for (int j = 0; j < 16; ++j) {
        int r = j * 4 + w;
        float4 v = *reinterpret_cast<const float4*>(
            src + (size_t)(kb + r) * DDIM + l * 4);
        float ss = v.x * v.x + v.y * v.y + v.z * v.z + v.w * v.w;
        #pragma unroll
        for (int off = 32; off > 0; off >>= 1) ss += __shfl_xor(ss, off);
        float inv = 1.0f / fmaxf(sqrtf(ss), 1e-8f);
        us4 u;
        u[0] = f2bu(v.x * inv); u[1] = f2bu(v.y * inv);
        u[2] = f2bu(v.z * inv); u[3] = f2bu(v.w * inv);
        *reinterpret_cast<us4*>(&lt[r * 260 + l * 4]) = u;
    }
    __syncthreads();
    int ko = tid & 7;          // k-octet 0..7
    int fq0 = tid >> 3;        // f-quad 0..31
    #pragma unroll
    for (int s = 0; s < 2; ++s) {
        int fq = fq0 + 32 * s;
        us4 rr[8];
        #pragma unroll
        for (int j = 0; j < 8; ++j)
            rr[j] = *reinterpret_cast<const us4*>(&lt[(ko * 8 + j) * 260 + fq * 4]);
        #pragma unroll
        for (int i = 0; i < 4; ++i) {
            us8 o;
            #pragma unroll
            for (int j = 0; j < 8; ++j) o[j] = rr[j][i];
            *reinterpret_cast<us8*>(
                &dst[(size_t)(fq * 4 + i) * N_ROWS + kb + ko * 8]) = o;
        }
    }
}

// ---- K2: no-LDS MFMA gram ----
// 2048 one-wave blocks = 64 positions (8x8 of 32x32) x 32 chunks.
// XCD-grouped: c = (bid&7)*4 + (bid>>9) -> a chunk's 64 position-blocks share
// one XCD; per-chunk obt working set = 256KB -> XCD-L2-resident re-reads.
// Fragments: 16B contiguous loads (lane = f-row, k-run of 8). No barriers.
__global__ __launch_bounds__(64) void gram_kernel(float* __restrict__ ws) {
    const unsigned short* obt = (const unsigned short*)ws + OBT_UOFF;
    unsigned short* part = (unsigned short*)ws + PART_UOFF;

    int bid = blockIdx.x;
    int c   = (bid & 7) * 4 + (bid >> 9);   // K-chunk 0..31
    int pos = (bid >> 3) & 63;              // 32x32 position
    int pm = pos >> 3, pn = pos & 7;
    int l = threadIdx.x;

    size_t fa = (size_t)(pm * 32 + (l & 31)) * N_ROWS;
    size_t fb = (size_t)(pn * 32 + (l & 31)) * N_ROWS;
    const unsigned short* Ao = obt + fa;
    const unsigned short* Bo = obt + fb;
    const unsigned short* At = obt + MAT_USZ + fa;
    const unsigned short* Bt = obt + MAT_USZ + fb;
    int kp = c * KC + ((l >> 5) * 8);       // lane k-base

    f32x16 aoo, att, aot;
    #pragma unroll
    for (int e = 0; e < 16; ++e) { aoo[e] = 0.f; att[e] = 0.f; aot[e] = 0.f; }

#define BCK(p) __builtin_bit_cast(bf16x8, *reinterpret_cast<const short8*>(p))
#define LDQ(A_, B_, C_, D_, s_) { int k = kp + (s_) * 16; \
    A_ = BCK(Ao + k); B_ = BCK(Bo + k); C_ = BCK(At + k); D_ = BCK(Bt + k); }
#define MMQ(A_, B_, C_, D_) { \
    aoo = __builtin_amdgcn_mfma_f32_32x32x16_bf16(A_, B_, aoo, 0, 0, 0); \
    att = __builtin_amdgcn_mfma_f32_32x32x16_bf16(C_, D_, att, 0, 0, 0); \
    aot = __builtin_amdgcn_mfma_f32_32x32x16_bf16(A_, D_, aot, 0, 0, 0); }

    bf16x8 a0, b0, c0, d0, a1, b1, c1, d1;
    LDQ(a0, b0, c0, d0, 0);
    LDQ(a1, b1, c1, d1, 1);
    #pragma unroll
    for (int s = 0; s < 16; s += 2) {       // KC/16 = 16 k-steps, depth-2 pipe
        MMQ(a0, b0, c0, d0);
        if (s + 2 < 16) LDQ(a0, b0, c0, d0, s + 2);
        MMQ(a1, b1, c1, d1);
        if (s + 3 < 16) LDQ(a1, b1, c1, d1, s + 3);
    }
#undef BCK
#undef LDQ
#undef MMQ

    // partials: [c][g][pos][1024]; C/D layout (m74/m101):
    // col = lane&31, row = (reg&3) + 8*(reg>>2) + 4*(lane>>5)
    size_t pb = (size_t)c * PART_STRIDE + (size_t)pos * 1024;
    #pragma unroll
    for (int reg = 0; reg < 16; ++reg) {
        int row = (reg & 3) + 8 * (reg >> 2) + ((l >> 5) << 2);
        int e = row * 32 + (l & 31);
        part[pb + 0 * NPOS * 1024 + e] = f2bu(aoo[reg]);
        part[pb + 1 * NPOS * 1024 + e] = f2bu(att[reg]);
        part[pb + 2 * NPOS * 1024 + e] = f2bu(aot[reg]);
    }
}

// ---- K3: chunk-sum + Frobenius combine; last block finalizes ----
__global__ __launch_bounds__(256) void reduce_kernel(const float* __restrict__ W,
                                                     float* __restrict__ out,
                                                     float* __restrict__ ws) {
    const unsigned short* part = (const unsigned short*)ws + PART_UOFF;
    u32* ctr = (u32*)(ws + 4);
    int tid = threadIdx.x;
    int gid = blockIdx.x * 256 + tid;             // 24576 threads
    size_t base = (size_t)gid * 8;
    float a[8];
    #pragma unroll
    for (int i = 0; i < 8; ++i) a[i] = 0.f;
    for (int cc = 0; cc < NC; ++cc) {
        us8 u = *reinterpret_cast<const us8*>(&part[(size_t)cc * PART_STRIDE + base]);
        #pragma unroll
        for (int i = 0; i < 8; ++i) a[i] += u2f(u[i]);
    }
    float s = 0.f;
    #pragma unroll
    for (int i = 0; i < 8; ++i) s += a[i] * a[i];
    int g = (int)(base >> 16);                    // gram id 0..2 within chunk
    if (g == 2) s = -2.0f * s;
    #pragma unroll
    for (int off = 32; off > 0; off >>= 1) s += __shfl_down(s, off);
    __shared__ float wsum[4];
    int l = tid & 63, w = tid >> 6;
    if (l == 0) wsum[w] = s;
    __syncthreads();
    if (tid == 0) {
        atomicAdd(&ws[0], wsum[0] + wsum[1] + wsum[2] + wsum[3]);
        __threadfence();
        unsigned int r = atomicAdd(&ctr[0], 1u);
        if (r == NRED - 1) {                      // last finishing block
            float v = __hip_atomic_load(&ws[0], __ATOMIC_ACQUIRE,
                                        __HIP_MEMORY_SCOPE_AGENT);
            out[0] = v * W[0] / ((float)N_ROWS * (float)N_ROWS);
        }
    }
}

extern "C" void kernel_launch(void* const* d_in, const int* in_sizes, int n_in,
                              void* d_out, int out_size, void* d_ws, size_t ws_size,
                              hipStream_t stream) {
    const float* O = (const float*)d_in[0];
    const float* T = (const float*)d_in[1];
    const float* W = (const float*)d_in[2];
    float* out = (float*)d_out;
    float* ws = (float*)d_ws;

    transpose_kernel<<<256, 256, 0, stream>>>(O, T, ws);
    gram_kernel<<<2048, 64, 0, stream>>>(ws);
    reduce_kernel<<<NRED, 256, 0, stream>>>(W, out, ws);
}